// Round 14
// baseline (107.403 us; speedup 1.0000x reference)
//
#include <hip/hip_runtime.h>

// Composite-filter formulation:
//   out[o] = sum_{k=0..54} Cp[r][k] * x[n0 - k],
//     r = (2o+32) % 3, n0 = (2o+32-r)/3,
//     Cp[p][k] = C[p+3k], C[j] = sum_m b[m]*h[j-2m]
//
// Session journal:
// R7:  direct-global windows: 46us, VALUBusy 22%.
// R8 FAILED: window reg double-buffer, VGPR 128, occupancy halved, 77us.
// R9:  LDS tile + XOR float4-slot swizzle slot(c)=c^((c>>3)&7). <42.6us.
// R10 FAILED: LDS coeff table (uniform ds_read_b128 not free) + path merge.
// R11: prep merge (3 dispatches -> 2). 117 -> 108.9.
// R12 FAILED: opaque-VGPR coeff idx + occupancy cap -> scratch spills.
//   Lesson: WRITE_SIZE explosion = spill detector.
// R13: single up-front ds burst: neutral. lgkmcnt-conflation REFUTED.
// R14: wave-autonomous staging, no __syncthreads. 107.4.
// R15: coeffs in 3 lane-resident VGPRs + readlane. VGPR 32, VALUBusy 38%,
//   fused wall UNCHANGED -> coeff-fetch REFUTED. 106.4 (BEST, reproduced
//   106.8).
// R16: 2-tile cross-tile pipeline: neutral. Convoy theory REFUTED.
// R17 FAILED correctness: 3 novel constructs bundled. Lesson: one per round.
// R18 regressed (130.6): per-block coeff build = serial-prefix chain.
//   Lesson: slack absorbs PARALLEL work, never SERIAL-PREFIX work.
// R19 FAILED correctness (absmax 7.3): waveless LDS bounce relied on
//   cross-lane RAW through LDS with no sync. Indexing audited sound.
//   Lesson: per-wave DS ordering is proven for WAR only; cross-lane RAW
//   needs a barrier.
// R20 (this): same store theory -- the one never-varied path. 48B-stride
//   stores = 48 lines/wave-store (3x TA line-requests on 49MB of writes,
//   feeding the unmeasured TA/L2 request pipe). Fix: BLOCK-level LDS
//   bounce with two __syncthreads (block-uniform branch; block 0 guarded
//   path unchanged). Write 3*tid+c (stride-3 coprime to 8-slot bank
//   period = minimal), read stride-1, 3 fully coalesced dwordx4 stores.

#define TPB 256
#define RPT 12                    // outputs per thread
#define OTILE (TPB * RPT)         // 3072 outputs per block
#define WREG 144                  // float4 slots per wave staging region
#define NTAPS 55
#define CPSTRIDE 56               // phase-major coeff stride (zero-padded)

#define SLOT(c) ((c) ^ (((c) >> 3) & 7))

// One dispatch, 3 independent blocks:
//   block 0: build cp[3*56] composite coefficients
//   block 1: head boundary (o in [0,50))
//   block 2: tail boundary (o in [n_out, out_size))
__global__ __launch_bounds__(TPB) void prep_k(
    const float* __restrict__ x, const float* __restrict__ h,
    const float* __restrict__ b, float* __restrict__ cp,
    float* __restrict__ out, int n_in, int n_out, int out_size)
{
    __shared__ float h_s[63];
    __shared__ float b_s[51];
    __shared__ float x_s[64];
    __shared__ float u_s[50];

    const int tid = threadIdx.x;
    if (tid < 63) h_s[tid] = h[tid];
    if (tid < 51) b_s[tid] = b[tid];

    if (blockIdx.x == 0) {
        __syncthreads();
        for (int idx = tid; idx < 3 * CPSTRIDE; idx += TPB) {
            const int p = idx / CPSTRIDE;
            const int k = idx - p * CPSTRIDE;
            float acc = 0.0f;
            if (k < NTAPS) {
                const int j = p + 3 * k;
                for (int m = 0; m <= 50; ++m) {
                    const int hi = j - 2 * m;
                    if (hi >= 0 && hi <= 62) acc += b_s[m] * h_s[hi];
                }
            }
            cp[idx] = acc;
        }
    } else if (blockIdx.x == 1) {
        if (tid < 44) x_s[tid] = (tid < n_in) ? x[tid] : 0.0f;
        __syncthreads();
        if (tid < 50) {
            const int s  = 2 * tid + 32;
            const int p0 = s % 3;
            const int q  = s / 3;
            float u = 0.0f;
            #pragma unroll
            for (int i = 0; i <= 20; ++i) {
                const int xi = q - i;
                u += h_s[p0 + 3 * i] * ((xi >= 0) ? x_s[xi] : 0.0f);
            }
            u_s[tid] = u;
        }
        __syncthreads();
        if (tid < 50) {
            float acc = 0.0f;
            for (int t = 0; t <= tid; ++t) acc += b_s[tid - t] * u_s[t];
            out[tid] = acc;
        }
    } else {
        const int t0   = n_out - 50;
        const int qmin = (2 * t0 + 32) / 3;
        const int xb   = qmin - 20;
        if (tid < 64) {
            const int xi = xb + tid;
            x_s[tid] = (xi >= 0 && xi < n_in) ? x[xi] : 0.0f;
        }
        __syncthreads();
        if (tid < 50) {
            const int t  = t0 + tid;
            const int s  = 2 * t + 32;
            const int p0 = s % 3;
            const int q  = s / 3;
            const int base = q - xb;
            float u = 0.0f;
            #pragma unroll
            for (int i = 0; i <= 20; ++i)
                u += h_s[p0 + 3 * i] * x_s[base - i];
            u_s[tid] = u;
        }
        __syncthreads();
        const int n_tail = out_size - n_out;   // 96
        if (tid < n_tail) {
            float acc = 0.0f;
            for (int j = tid; j <= 49; ++j) acc += b_s[tid + 50 - j] * u_s[j];
            out[n_out + tid] = acc;
        }
    }
}

// Coefficient fetch: flat index i (compile-time constant) -> value held in
// lane (i&63) of table reg (i>>6). readlane result is wave-uniform (SGPR).
__device__ __forceinline__ float co(const int i, const int c0,
                                    const int c1, const int c2) {
    const int ln = i & 63;
    const int v = (i < 64)  ? __builtin_amdgcn_readlane(c0, ln)
                : (i < 128) ? __builtin_amdgcn_readlane(c1, ln)
                            : __builtin_amdgcn_readlane(c2, ln);
    return __int_as_float(v);
}

// Group g covers taps k=4g..4g+3 for 12 outputs d=0..11.
// delta_d = {0,1,2,2,3,4,4,5,6,6,7,8}, phase r_d = (2+2d)%3 -> q2/q1/q0 cycle.
// Flat coeff idx: q0 = 4g+j, q1 = 56+4g+j, q2 = 112+4g+j.
#define GRP12(g, A, B, C, D) {                                          \
    const float q2x = co(112 + 4*(g), cc0, cc1, cc2);                   \
    const float q2y = co(113 + 4*(g), cc0, cc1, cc2);                   \
    const float q2z = co(114 + 4*(g), cc0, cc1, cc2);                   \
    const float q2w = co(115 + 4*(g), cc0, cc1, cc2);                   \
    const float q1x = co( 56 + 4*(g), cc0, cc1, cc2);                   \
    const float q1y = co( 57 + 4*(g), cc0, cc1, cc2);                   \
    const float q1z = co( 58 + 4*(g), cc0, cc1, cc2);                   \
    const float q1w = co( 59 + 4*(g), cc0, cc1, cc2);                   \
    const float q0x = co(      4*(g), cc0, cc1, cc2);                   \
    const float q0y = co(  1 + 4*(g), cc0, cc1, cc2);                   \
    const float q0z = co(  2 + 4*(g), cc0, cc1, cc2);                   \
    const float q0w = co(  3 + 4*(g), cc0, cc1, cc2);                   \
    /* j=0 */                                                           \
    a0  += q2x * C.z;  a1  += q1x * C.w;  a2  += q0x * B.x;             \
    a3  += q2x * B.x;  a4  += q1x * B.y;  a5  += q0x * B.z;             \
    a6  += q2x * B.z;  a7  += q1x * B.w;  a8  += q0x * A.x;             \
    a9  += q2x * A.x;  a10 += q1x * A.y;  a11 += q0x * A.z;             \
    /* j=1 */                                                           \
    a0  += q2y * C.y;  a1  += q1y * C.z;  a2  += q0y * C.w;             \
    a3  += q2y * C.w;  a4  += q1y * B.x;  a5  += q0y * B.y;             \
    a6  += q2y * B.y;  a7  += q1y * B.z;  a8  += q0y * B.w;             \
    a9  += q2y * B.w;  a10 += q1y * A.x;  a11 += q0y * A.y;             \
    /* j=2 */                                                           \
    a0  += q2z * C.x;  a1  += q1z * C.y;  a2  += q0z * C.z;             \
    a3  += q2z * C.z;  a4  += q1z * C.w;  a5  += q0z * B.x;             \
    a6  += q2z * B.x;  a7  += q1z * B.y;  a8  += q0z * B.z;             \
    a9  += q2z * B.z;  a10 += q1z * B.w;  a11 += q0z * A.x;             \
    /* j=3 */                                                           \
    a0  += q2w * D.w;  a1  += q1w * C.x;  a2  += q0w * C.y;             \
    a3  += q2w * C.y;  a4  += q1w * C.z;  a5  += q0w * C.w;             \
    a6  += q2w * C.w;  a7  += q1w * B.x;  a8  += q0w * B.y;             \
    a9  += q2w * B.y;  a10 += q1w * B.z;  a11 += q0w * B.w; }

// Tail group: j=0..2 only (k = 52,53,54).
#define GRP12T(g, A, B, C) {                                            \
    const float q2x = co(112 + 4*(g), cc0, cc1, cc2);                   \
    const float q2y = co(113 + 4*(g), cc0, cc1, cc2);                   \
    const float q2z = co(114 + 4*(g), cc0, cc1, cc2);                   \
    const float q1x = co( 56 + 4*(g), cc0, cc1, cc2);                   \
    const float q1y = co( 57 + 4*(g), cc0, cc1, cc2);                   \
    const float q1z = co( 58 + 4*(g), cc0, cc1, cc2);                   \
    const float q0x = co(      4*(g), cc0, cc1, cc2);                   \
    const float q0y = co(  1 + 4*(g), cc0, cc1, cc2);                   \
    const float q0z = co(  2 + 4*(g), cc0, cc1, cc2);                   \
    a0  += q2x * C.z;  a1  += q1x * C.w;  a2  += q0x * B.x;             \
    a3  += q2x * B.x;  a4  += q1x * B.y;  a5  += q0x * B.z;             \
    a6  += q2x * B.z;  a7  += q1x * B.w;  a8  += q0x * A.x;             \
    a9  += q2x * A.x;  a10 += q1x * A.y;  a11 += q0x * A.z;             \
    a0  += q2y * C.y;  a1  += q1y * C.z;  a2  += q0y * C.w;             \
    a3  += q2y * C.w;  a4  += q1y * B.x;  a5  += q0y * B.y;             \
    a6  += q2y * B.y;  a7  += q1y * B.z;  a8  += q0y * B.w;             \
    a9  += q2y * B.w;  a10 += q1y * A.x;  a11 += q0y * A.y;             \
    a0  += q2z * C.x;  a1  += q1z * C.y;  a2  += q0z * C.z;             \
    a3  += q2z * C.z;  a4  += q1z * C.w;  a5  += q0z * B.x;             \
    a6  += q2z * B.x;  a7  += q1z * B.y;  a8  += q0z * B.z;             \
    a9  += q2z * B.z;  a10 += q1z * B.w;  a11 += q0z * A.x; }

__global__ __launch_bounds__(TPB) void fused_fast(
    const float* __restrict__ x, const float* __restrict__ cp,
    float* __restrict__ out, int n_in, int n_out)
{
    // 12288 B: staging uses [0,576) as 4x144 per-wave regions;
    // the store bounce reuses all 768 slots after a barrier.
    __shared__ float4 xs4[768];

    const int tid = threadIdx.x;
    const int w   = tid >> 6;                    // wave id 0..3
    const int l   = tid & 63;                    // lane
    const int bt  = blockIdx.x;
    const int o0  = bt * OTILE;                  // multiple of 3072
    const int n_tile0 = 2048 * bt - 44;          // tile x-base, multiple of 4
    const int wreg = w * WREG;                   // this wave's staging region

    // ---- lane-resident coefficient table: 3 VGPRs cover all 168 floats ----
    const int cc0 = __float_as_int(cp[l]);
    const int cc1 = __float_as_int(cp[l + 64]);
    const int cc2 = __float_as_int(cp[(l < 40) ? (128 + l) : 128]);

    // ---- wave-autonomous staging (R14): lane l stages local chunks l,
    //      l+64, (l<14) l+128. No barrier before compute.
    const bool interior = (n_tile0 >= 0) && (n_tile0 + 2104 <= n_in);
    if (interior) {
        const float4* gw = (const float4*)(x + n_tile0) + 128 * w;
        const float4 g0 = gw[l];
        const float4 g1 = gw[l + 64];
        xs4[wreg + SLOT(l)]      = g0;
        xs4[wreg + SLOT(l + 64)] = g1;
        if (l < 14) {
            xs4[wreg + SLOT(l + 128)] = gw[l + 128];
        }
    } else {
        const int fb0 = n_tile0 + 512 * w;       // float base of wave window
        #pragma unroll
        for (int s = 0; s < 3; ++s) {
            const int c = l + 64 * s;            // local chunk
            if (c > 141) break;
            const int fb = fb0 + 4 * c;
            float4 v;
            v.x = (fb + 0 >= 0 && fb + 0 < n_in) ? x[fb + 0] : 0.0f;
            v.y = (fb + 1 >= 0 && fb + 1 < n_in) ? x[fb + 1] : 0.0f;
            v.z = (fb + 2 >= 0 && fb + 2 < n_in) ? x[fb + 2] : 0.0f;
            v.w = (fb + 3 >= 0 && fb + 3 < n_in) ? x[fb + 3] : 0.0f;
            xs4[wreg + SLOT(c)] = v;
        }
    }

    float a0 = 0.f, a1 = 0.f, a2 = 0.f, a3  = 0.f, a4  = 0.f, a5  = 0.f;
    float a6 = 0.f, a7 = 0.f, a8 = 0.f, a9  = 0.f, a10 = 0.f, a11 = 0.f;

    // ---- compute: 6-reg rotating window over local chunks 2l+15 .. 2l ----
#define XS(j) xs4[wreg + SLOT(2 * l + (j))]
    {
        float4 r0 = XS(15), r1 = XS(14), r2 = XS(13),
               r3 = XS(12), r4 = XS(11), r5 = XS(10);
        GRP12( 0, r0, r1, r2, r3);  r0 = XS(9);
        GRP12( 1, r1, r2, r3, r4);  r1 = XS(8);
        GRP12( 2, r2, r3, r4, r5);  r2 = XS(7);
        GRP12( 3, r3, r4, r5, r0);  r3 = XS(6);
        GRP12( 4, r4, r5, r0, r1);  r4 = XS(5);
        GRP12( 5, r5, r0, r1, r2);  r5 = XS(4);
        GRP12( 6, r0, r1, r2, r3);  r0 = XS(3);
        GRP12( 7, r1, r2, r3, r4);  r1 = XS(2);
        GRP12( 8, r2, r3, r4, r5);  r2 = XS(1);
        GRP12( 9, r3, r4, r5, r0);  r3 = XS(0);
        GRP12(10, r4, r5, r0, r1);
        GRP12(11, r5, r0, r1, r2);
        GRP12(12, r0, r1, r2, r3);
        GRP12T(13, r1, r2, r3);
    }
#undef XS

    // ---- store 12 outputs ----
    // R20: block-level LDS bounce with barrier sync (block-uniform branch:
    // o0 is per-block, so all threads of a block take the same arm; block 0
    // never reaches the barriers). Thread tid's quads -> block-local float4
    // indices 3*tid+c (stride-3 coprime to the 8-slot bank period ->
    // minimal-cost b128 writes). Read back stride-1, store 3 coalesced
    // dwordx4 (16 lines per wave-store vs 48 on the old 48B-stride path).
    if (o0 >= 50) {
        const float4 av0 = make_float4(a0, a1, a2,  a3);
        const float4 av1 = make_float4(a4, a5, a6,  a7);
        const float4 av2 = make_float4(a8, a9, a10, a11);
        __syncthreads();                         // all window reads done
        const int j0 = 3 * tid;                  // block-local out float4 idx
        xs4[j0]     = av0;
        xs4[j0 + 1] = av1;
        xs4[j0 + 2] = av2;
        __syncthreads();                         // writes visible block-wide
        float4* const ob4 = (float4*)(out + o0); // 16B aligned (o0 % 4 == 0)
        ob4[tid]       = xs4[tid];
        ob4[256 + tid] = xs4[256 + tid];
        ob4[512 + tid] = xs4[512 + tid];
    } else {
        const int ob = o0 + RPT * tid;           // multiple of 12
        const float accs[RPT] = {a0, a1, a2, a3, a4, a5, a6, a7, a8, a9, a10, a11};
#pragma unroll
        for (int d = 0; d < RPT; ++d) {
            const int o = ob + d;
            if (o >= 50 && o < n_out) out[o] = accs[d];
        }
    }
}

extern "C" void kernel_launch(void* const* d_in, const int* in_sizes, int n_in_arrs,
                              void* d_out, int out_size, void* d_ws, size_t ws_size,
                              hipStream_t stream) {
    const float* x = (const float*)d_in[0];
    const float* h = (const float*)d_in[1];
    const float* b = (const float*)d_in[2];
    float* out = (float*)d_out;
    float* cp  = (float*)d_ws;                        // 3*56*4 = 672 bytes

    const int n_in  = in_sizes[0];                    // 8388608
    const int n_out = (int)((long long)n_in * 3 / 2); // 12582912

    prep_k<<<3, TPB, 0, stream>>>(x, h, b, cp, out, n_in, n_out, out_size);

    const int nblocks = (n_out + OTILE - 1) / OTILE;  // 4096
    fused_fast<<<nblocks, TPB, 0, stream>>>(x, cp, out, n_in, n_out);
}